// Round 6
// baseline (607.418 us; speedup 1.0000x reference)
//
#include <hip/hip_runtime.h>
#include <math.h>

#define BATCH 2
#define NCH 21
#define CPAD 24            // channels padded to 24 (48 B fp16 per pixel)
#define HH 512
#define WW 512
#define KS 5
#define RAD 2
#define NTAPS 25
#define NUM_ITERS 10

// weights-kernel tile geometry
#define TXW 32
#define TYW 8
#define HXW (TXW + 2*RAD)   // 36
#define HYW (TYW + 2*RAD)   // 12
#define HPXW (HXW * HYW)    // 432

// iter-kernel tile geometry: 32x16 px, 256 threads, 2 px (horizontal pair) per thread
#define TW 32
#define TH 16
#define HX2 (TW + 2*RAD)    // 36
#define HY2 (TH + 2*RAD)    // 20
#define HPX2 (HX2 * HY2)    // 720
#define NCHUNK (HPX2 * 3)   // 2160 16-byte chunks

typedef _Float16 f16;
typedef _Float16 half8 __attribute__((ext_vector_type(8)));
typedef _Float16 half2v __attribute__((ext_vector_type(2)));

__device__ __forceinline__ int refl(int i, int n) {
    if (i < 0) i = -i;
    if (i >= n) i = 2*n - 2 - i;
    return i;
}

// weight-element selector (t is a compile-time constant after unrolling)
#define WSEL(h0, h1, h2, hl, t) \
    ((t) < 8 ? (h0)[(t)] : (t) < 16 ? (h1)[(t) - 8] : (t) < 24 ? (h2)[(t) - 16] : (hl))

// ---------------- Kernel A: combined normalized weights ----------------
// out layout: wcA[px][24 halfs] (taps 0..23, 48B interleaved) + wcB16[px] (tap 24)
__global__ __launch_bounds__(256) void weights_kernel(const float* __restrict__ image,
                                                      const float* __restrict__ edges,
                                                      f16* __restrict__ wcA,
                                                      f16* __restrict__ wcB16) {
    __shared__ float sr_[HYW][HXW];
    __shared__ float sg_[HYW][HXW];
    __shared__ float sb_[HYW][HXW];
    __shared__ float se_[HYW][HXW];

    const int tx = threadIdx.x;
    const int ty = threadIdx.y;
    const int tid = ty * TXW + tx;
    const int x0 = blockIdx.x * TXW;
    const int y0 = blockIdx.y * TYW;
    const int b = blockIdx.z;
    const int x = x0 + tx;
    const int y = y0 + ty;
    const size_t plane = (size_t)HH * WW;
    const float* img = image + (size_t)b * 3 * plane;
    const float* edg = edges + (size_t)b * plane;

    for (int i = tid; i < HPXW; i += TXW * TYW) {
        int ly = i / HXW, lx = i - ly * HXW;
        int gy = refl(y0 + ly - RAD, HH);
        int gx = refl(x0 + lx - RAD, WW);
        int g = gy * WW + gx;
        sr_[ly][lx] = img[g];
        sg_[ly][lx] = img[plane + g];
        sb_[ly][lx] = img[2 * plane + g];
        se_[ly][lx] = edg[g];
    }
    __syncthreads();

    float gs[3];
    gs[0] = 1.0f; gs[1] = __expf(-1.0f / 50.0f); gs[2] = __expf(-4.0f / 50.0f);
    float gb[3];
    gb[0] = 1.0f; gb[1] = __expf(-2.0f); gb[2] = __expf(-8.0f);
    float gbs = gb[0] + 2.0f * (gb[1] + gb[2]);
    gb[0] /= gbs; gb[1] /= gbs; gb[2] /= gbs;

    const float r0 = sr_[ty + RAD][tx + RAD];
    const float g0 = sg_[ty + RAD][tx + RAD];
    const float b0 = sb_[ty + RAD][tx + RAD];
    const float e0 = se_[ty + RAD][tx + RAD];

    float wr[NTAPS], we[NTAPS];
    float sr = 0.f, se = 0.f;
#pragma unroll
    for (int dy = 0; dy < KS; dy++) {
#pragma unroll
        for (int dx = 0; dx < KS; dx++) {
            float sp = gs[abs(dy - RAD)] * gs[abs(dx - RAD)];
            float d = fabsf(sr_[ty + dy][tx + dx] - r0)
                    + fabsf(sg_[ty + dy][tx + dx] - g0)
                    + fabsf(sb_[ty + dy][tx + dx] - b0);
            float w1 = sp * __expf(-2.0f * d * d);
            float de = fabsf(se_[ty + dy][tx + dx] - e0);
            float w2 = sp * __expf(-2.0f * de * de);
            wr[dy * KS + dx] = w1;
            we[dy * KS + dx] = w2;
            sr += w1;
            se += w2;
        }
    }
    float isr = 1.0f / sr, ise = 1.0f / se;
    float wt[NTAPS];
#pragma unroll
    for (int t = 0; t < NTAPS; t++) {
        int dy = t / KS, dx = t % KS;
        float g2 = gb[abs(dy - RAD)] * gb[abs(dx - RAD)];
        wt[t] = g2 + wr[t] * isr + we[t] * ise;
    }
    const size_t pixoff = (size_t)b * plane + (size_t)y * WW + x;
    half8* wo = (half8*)(wcA + pixoff * 24);
#pragma unroll
    for (int g = 0; g < 3; g++) {
        half8 v;
#pragma unroll
        for (int k = 0; k < 8; k++) v[k] = (f16)wt[g * 8 + k];
        wo[g] = v;
    }
    wcB16[pixoff] = (f16)wt[24];
}

// ---------------- Kernel B: initial softmax -> interleaved fp16 q + fp16 unary ----------------
__global__ void init_kernel(const float* __restrict__ unary,
                            f16* __restrict__ q,
                            f16* __restrict__ u16) {
    int idx = blockIdx.x * blockDim.x + threadIdx.x;
    if (idx >= BATCH * HH * WW) return;
    int p = idx % (HH * WW);
    int b = idx / (HH * WW);
    const size_t plane = (size_t)HH * WW;
    const float* u = unary + (size_t)b * NCH * plane + p;
    float l[CPAD];
    float m = -1e30f;
#pragma unroll
    for (int c = 0; c < NCH; c++) { l[c] = u[c * plane]; m = fmaxf(m, l[c]); }
    l[21] = 0.f; l[22] = 0.f; l[23] = 0.f;

    half8* uo = (half8*)(u16 + ((size_t)b * plane + p) * CPAD);
#pragma unroll
    for (int g = 0; g < 3; g++) {
        half8 v;
#pragma unroll
        for (int k = 0; k < 8; k++) v[k] = (f16)l[g * 8 + k];
        uo[g] = v;
    }

    float s = 0.f;
    float e[CPAD];
#pragma unroll
    for (int c = 0; c < NCH; c++) { e[c] = __expf(l[c] - m); s += e[c]; }
    float is = 1.0f / s;
    e[21] = 0.f; e[22] = 0.f; e[23] = 0.f;
    half8* qo = (half8*)(q + ((size_t)b * plane + p) * CPAD);
#pragma unroll
    for (int g = 0; g < 3; g++) {
        half8 v;
#pragma unroll
        for (int k = 0; k < 8; k++) v[k] = (f16)(e[g * 8 + k] * is);
        qo[g] = v;
    }
}

// ---------------- Kernel C: one fused CRF iteration, 2 px per thread ----------------
template <bool FINAL>
__global__ __launch_bounds__(256, 4) void crf_iter_kernel(const f16* __restrict__ qin,
                                                          const f16* __restrict__ u16,
                                                          const f16* __restrict__ wcA,
                                                          const f16* __restrict__ wcB16,
                                                          void* __restrict__ qout) {
    __shared__ __align__(16) f16 tileH[HPX2][CPAD];   // 34560 B

    const int tid = threadIdx.x;          // 0..255
    const int txh = tid & 15;             // 0..15 (pixel pair column)
    const int tyh = tid >> 4;             // 0..15 (row)

    // XCD band swizzle: 1024 blocks; XCD (flat%8) owns 4 tile-rows per batch
    const int flat = blockIdx.x;
    const int band = flat & 7;
    const int within = flat >> 3;         // 0..127
    const int b = within >> 6;
    const int r = within & 63;
    const int x0 = (r & 15) * TW;
    const int y0 = (band * 4 + (r >> 4)) * TH;
    const int x = x0 + txh * 2;
    const int y = y0 + tyh;
    const size_t plane = (size_t)HH * WW;

    // ---- async stage 20x36 halo (fp16, interleaved) straight into LDS ----
    const f16* qb = qin + (size_t)b * plane * CPAD;
    f16* lbase = &tileH[0][0];
    for (int idx = tid; idx < NCHUNK; idx += 256) {
        int px = idx / 3, h4 = idx - px * 3;
        int ly = px / HX2, lx = px - ly * HX2;
        int gy = refl(y0 + ly - RAD, HH);
        int gx = refl(x0 + lx - RAD, WW);
        const f16* g = qb + ((size_t)(gy * WW + gx)) * CPAD + h4 * 8;
        __builtin_amdgcn_global_load_lds(
            (const __attribute__((address_space(1))) void*)g,
            (__attribute__((address_space(3))) void*)(lbase + (size_t)idx * 8),
            16, 0, 0);
    }

    // ---- prefetch both pixels' weights while staging is in flight ----
    const size_t pixoff = (size_t)b * plane + (size_t)y * WW + x;
    const half8* wpa = (const half8*)(wcA + pixoff * 24);
    half8 wa0 = wpa[0], wa1 = wpa[1], wa2 = wpa[2];
    half8 wb0 = wpa[3], wb1 = wpa[4], wb2 = wpa[5];
    half2v wl = *(const half2v*)(wcB16 + pixoff);   // tap 24 for px0 (lo) and px1 (hi)

    __syncthreads();   // drains LDS-DMA + weight loads, joins block

    // ---- 25-tap weighted gather, 2 adjacent px share the 5x6 window ----
    float acc0[NCH], acc1[NCH];
#pragma unroll
    for (int c = 0; c < NCH; c++) { acc0[c] = 0.f; acc1[c] = 0.f; }

#pragma unroll
    for (int dy = 0; dy < KS; dy++) {
        const f16* rowp = &tileH[(tyh + dy) * HX2 + txh * 2][0];
#pragma unroll
        for (int j = 0; j < 6; j++) {
            const f16* tp = rowp + j * CPAD;
            half8 v0 = *(const half8*)(tp);
            half8 v1 = *(const half8*)(tp + 8);
            half8 v2 = *(const half8*)(tp + 16);
            if (j < 5) {
                const int t = dy * KS + j;
                const float w = (float)WSEL(wa0, wa1, wa2, wl[0], t);
#pragma unroll
                for (int k = 0; k < 8; k++) acc0[k]      = fmaf((float)v0[k], w, acc0[k]);
#pragma unroll
                for (int k = 0; k < 8; k++) acc0[8 + k]  = fmaf((float)v1[k], w, acc0[8 + k]);
#pragma unroll
                for (int k = 0; k < 5; k++) acc0[16 + k] = fmaf((float)v2[k], w, acc0[16 + k]);
            }
            if (j >= 1) {
                const int t = dy * KS + j - 1;
                const float w = (float)WSEL(wb0, wb1, wb2, wl[1], t);
#pragma unroll
                for (int k = 0; k < 8; k++) acc1[k]      = fmaf((float)v0[k], w, acc1[k]);
#pragma unroll
                for (int k = 0; k < 8; k++) acc1[8 + k]  = fmaf((float)v1[k], w, acc1[8 + k]);
#pragma unroll
                for (int k = 0; k < 5; k++) acc1[16 + k] = fmaf((float)v2[k], w, acc1[16 + k]);
            }
        }
    }

    // ---- logits + softmax for both pixels (in place) ----
    const half8* ub = (const half8*)(u16 + pixoff * CPAD);
    {
        half8 u0 = ub[0], u1 = ub[1], u2 = ub[2];
#pragma unroll
        for (int k = 0; k < 8; k++) acc0[k] = (float)u0[k] - acc0[k];
#pragma unroll
        for (int k = 0; k < 8; k++) acc0[8 + k] = (float)u1[k] - acc0[8 + k];
#pragma unroll
        for (int k = 0; k < 5; k++) acc0[16 + k] = (float)u2[k] - acc0[16 + k];
        u0 = ub[3]; u1 = ub[4]; u2 = ub[5];
#pragma unroll
        for (int k = 0; k < 8; k++) acc1[k] = (float)u0[k] - acc1[k];
#pragma unroll
        for (int k = 0; k < 8; k++) acc1[8 + k] = (float)u1[k] - acc1[8 + k];
#pragma unroll
        for (int k = 0; k < 5; k++) acc1[16 + k] = (float)u2[k] - acc1[16 + k];
    }

    float m0 = acc0[0], m1 = acc1[0];
#pragma unroll
    for (int c = 1; c < NCH; c++) { m0 = fmaxf(m0, acc0[c]); m1 = fmaxf(m1, acc1[c]); }
    float s0 = 0.f, s1 = 0.f;
#pragma unroll
    for (int c = 0; c < NCH; c++) {
        acc0[c] = __expf(acc0[c] - m0); s0 += acc0[c];
        acc1[c] = __expf(acc1[c] - m1); s1 += acc1[c];
    }
    float is0 = 1.0f / s0, is1 = 1.0f / s1;

    if (FINAL) {
        float* qo = (float*)qout + (size_t)b * NCH * plane + (size_t)y * WW + x;
#pragma unroll
        for (int c = 0; c < NCH; c++) {
            float2 v = make_float2(acc0[c] * is0, acc1[c] * is1);
            *(float2*)(qo + (size_t)c * plane) = v;
        }
    } else {
        half8* qo = (half8*)((f16*)qout + pixoff * CPAD);
        half8 o0, o1, o2;
#pragma unroll
        for (int k = 0; k < 8; k++)  o0[k] = (f16)(acc0[k] * is0);
#pragma unroll
        for (int k = 0; k < 8; k++)  o1[k] = (f16)(acc0[8 + k] * is0);
#pragma unroll
        for (int k = 0; k < 5; k++)  o2[k] = (f16)(acc0[16 + k] * is0);
        o2[5] = (f16)0.f; o2[6] = (f16)0.f; o2[7] = (f16)0.f;
        qo[0] = o0; qo[1] = o1; qo[2] = o2;
#pragma unroll
        for (int k = 0; k < 8; k++)  o0[k] = (f16)(acc1[k] * is1);
#pragma unroll
        for (int k = 0; k < 8; k++)  o1[k] = (f16)(acc1[8 + k] * is1);
#pragma unroll
        for (int k = 0; k < 5; k++)  o2[k] = (f16)(acc1[16 + k] * is1);
        o2[5] = (f16)0.f; o2[6] = (f16)0.f; o2[7] = (f16)0.f;
        qo[3] = o0; qo[4] = o1; qo[5] = o2;
    }
}

extern "C" void kernel_launch(void* const* d_in, const int* in_sizes, int n_in,
                              void* d_out, int out_size, void* d_ws, size_t ws_size,
                              hipStream_t stream) {
    const float* unary = (const float*)d_in[0];   // B,21,512,512
    const float* image = (const float*)d_in[1];   // B,3,512,512
    const float* edges = (const float*)d_in[2];   // B,512,512
    float* out = (float*)d_out;                   // B,21,512,512 fp32

    const size_t plane = (size_t)HH * WW;
    char* ws = (char*)d_ws;
    f16* wcA = (f16*)ws;                                         // B*plane*24 f16 = 25.2 MB
    char* p1 = ws + sizeof(f16) * BATCH * plane * 24;
    f16* wcB16 = (f16*)p1;                                       // B*plane f16    =  1.0 MB
    char* p2 = p1 + sizeof(f16) * BATCH * plane;
    f16* u16 = (f16*)p2;                                         // 25.2 MB
    char* p3 = p2 + sizeof(f16) * BATCH * plane * CPAD;
    f16* qA = (f16*)p3;                                          // 25.2 MB
    f16* qB = qA + (size_t)BATCH * plane * CPAD;                 // 25.2 MB (total ~102 MB)

    const int npix = BATCH * HH * WW;
    dim3 gridW(WW / TXW, HH / TYW, BATCH);
    dim3 blockW(TXW, TYW, 1);
    weights_kernel<<<gridW, blockW, 0, stream>>>(image, edges, wcA, wcB16);
    init_kernel<<<(npix + 255) / 256, 256, 0, stream>>>(unary, qA, u16);

    const int nblk = (WW / TW) * (HH / TH) * BATCH;   // 1024
    f16* qa = qA;
    f16* qb = qB;
    for (int it = 0; it < NUM_ITERS - 1; it++) {
        crf_iter_kernel<false><<<nblk, 256, 0, stream>>>(qa, u16, wcA, wcB16, (void*)qb);
        f16* t = qa; qa = qb; qb = t;
    }
    crf_iter_kernel<true><<<nblk, 256, 0, stream>>>(qa, u16, wcA, wcB16, (void*)out);
}

// Round 7
// 333.075 us; speedup vs baseline: 1.8237x; 1.8237x over previous
//
#include <hip/hip_runtime.h>
#include <math.h>

#define BATCH 2
#define NCH 21
#define CPAD 24            // channels padded to 24 (48 B fp16 per pixel)
#define HH 512
#define WW 512
#define KS 5
#define RAD 2
#define NTAPS 25
#define NPAIR 13           // 25 taps packed as 13 half2 pairs (last hi = 0)
#define NUM_ITERS 10

// weights-kernel tile geometry
#define TXW 32
#define TYW 8
#define HXW (TXW + 2*RAD)   // 36
#define HYW (TYW + 2*RAD)   // 12
#define HPXW (HXW * HYW)    // 432

// iter-kernel tile geometry: 32x16 px, 512 threads, 1 px per thread
#define TW 32
#define TH 16
#define NTHR 512
#define HX2 (TW + 2*RAD)    // 36
#define HY2 (TH + 2*RAD)    // 20
#define HPX2 (HX2 * HY2)    // 720
#define NCHUNK (HPX2 * 3)   // 2160 16-byte chunks

typedef _Float16 f16;
typedef _Float16 half8 __attribute__((ext_vector_type(8)));
typedef _Float16 half2v __attribute__((ext_vector_type(2)));

__device__ __forceinline__ int refl(int i, int n) {
    if (i < 0) i = -i;
    if (i >= n) i = 2*n - 2 - i;
    return i;
}

// ---------------- Kernel A: combined normalized weights, LDS-tiled guide ----------------
// w[tap] = G2d_norm + w_rgb/sum + w_edge/sum; layout wc2[b][pair][y][x] = half2
__global__ __launch_bounds__(256) void weights_kernel(const float* __restrict__ image,
                                                      const float* __restrict__ edges,
                                                      half2v* __restrict__ wc2) {
    __shared__ float sr_[HYW][HXW];
    __shared__ float sg_[HYW][HXW];
    __shared__ float sb_[HYW][HXW];
    __shared__ float se_[HYW][HXW];

    const int tx = threadIdx.x;
    const int ty = threadIdx.y;
    const int tid = ty * TXW + tx;
    const int x0 = blockIdx.x * TXW;
    const int y0 = blockIdx.y * TYW;
    const int b = blockIdx.z;
    const int x = x0 + tx;
    const int y = y0 + ty;
    const size_t plane = (size_t)HH * WW;
    const float* img = image + (size_t)b * 3 * plane;
    const float* edg = edges + (size_t)b * plane;

    for (int i = tid; i < HPXW; i += TXW * TYW) {
        int ly = i / HXW, lx = i - ly * HXW;
        int gy = refl(y0 + ly - RAD, HH);
        int gx = refl(x0 + lx - RAD, WW);
        int g = gy * WW + gx;
        sr_[ly][lx] = img[g];
        sg_[ly][lx] = img[plane + g];
        sb_[ly][lx] = img[2 * plane + g];
        se_[ly][lx] = edg[g];
    }
    __syncthreads();

    float gs[3];
    gs[0] = 1.0f; gs[1] = __expf(-1.0f / 50.0f); gs[2] = __expf(-4.0f / 50.0f);
    float gb[3];
    gb[0] = 1.0f; gb[1] = __expf(-2.0f); gb[2] = __expf(-8.0f);
    float gbs = gb[0] + 2.0f * (gb[1] + gb[2]);
    gb[0] /= gbs; gb[1] /= gbs; gb[2] /= gbs;

    const float r0 = sr_[ty + RAD][tx + RAD];
    const float g0 = sg_[ty + RAD][tx + RAD];
    const float b0 = sb_[ty + RAD][tx + RAD];
    const float e0 = se_[ty + RAD][tx + RAD];

    float wr[NTAPS], we[NTAPS];
    float sr = 0.f, se = 0.f;
#pragma unroll
    for (int dy = 0; dy < KS; dy++) {
#pragma unroll
        for (int dx = 0; dx < KS; dx++) {
            float sp = gs[abs(dy - RAD)] * gs[abs(dx - RAD)];
            float d = fabsf(sr_[ty + dy][tx + dx] - r0)
                    + fabsf(sg_[ty + dy][tx + dx] - g0)
                    + fabsf(sb_[ty + dy][tx + dx] - b0);
            float w1 = sp * __expf(-2.0f * d * d);
            float de = fabsf(se_[ty + dy][tx + dx] - e0);
            float w2 = sp * __expf(-2.0f * de * de);
            wr[dy * KS + dx] = w1;
            we[dy * KS + dx] = w2;
            sr += w1;
            se += w2;
        }
    }
    float isr = 1.0f / sr, ise = 1.0f / se;
    float wt[NTAPS + 1];
#pragma unroll
    for (int t = 0; t < NTAPS; t++) {
        int dy = t / KS, dx = t % KS;
        float g2 = gb[abs(dy - RAD)] * gb[abs(dx - RAD)];
        wt[t] = g2 + wr[t] * isr + we[t] * ise;
    }
    wt[NTAPS] = 0.f;
#pragma unroll
    for (int p = 0; p < NPAIR; p++) {
        half2v h;
        h[0] = (f16)wt[2 * p];
        h[1] = (f16)wt[2 * p + 1];
        wc2[((size_t)b * NPAIR + p) * plane + (size_t)y * WW + x] = h;
    }
}

// ---------------- Kernel B: initial softmax -> interleaved fp16 q + fp16 unary ----------------
__global__ void init_kernel(const float* __restrict__ unary,
                            f16* __restrict__ q,
                            f16* __restrict__ u16) {
    int idx = blockIdx.x * blockDim.x + threadIdx.x;
    if (idx >= BATCH * HH * WW) return;
    int p = idx % (HH * WW);
    int b = idx / (HH * WW);
    const size_t plane = (size_t)HH * WW;
    const float* u = unary + (size_t)b * NCH * plane + p;
    float l[CPAD];
    float m = -1e30f;
#pragma unroll
    for (int c = 0; c < NCH; c++) { l[c] = u[c * plane]; m = fmaxf(m, l[c]); }
    l[21] = 0.f; l[22] = 0.f; l[23] = 0.f;

    half8* uo = (half8*)(u16 + ((size_t)b * plane + p) * CPAD);
#pragma unroll
    for (int g = 0; g < 3; g++) {
        half8 v;
#pragma unroll
        for (int k = 0; k < 8; k++) v[k] = (f16)l[g * 8 + k];
        uo[g] = v;
    }

    float s = 0.f;
    float e[CPAD];
#pragma unroll
    for (int c = 0; c < NCH; c++) { e[c] = __expf(l[c] - m); s += e[c]; }
    float is = 1.0f / s;
    e[21] = 0.f; e[22] = 0.f; e[23] = 0.f;
    half8* qo = (half8*)(q + ((size_t)b * plane + p) * CPAD);
#pragma unroll
    for (int g = 0; g < 3; g++) {
        half8 v;
#pragma unroll
        for (int k = 0; k < 8; k++) v[k] = (f16)(e[g * 8 + k] * is);
        qo[g] = v;
    }
}

// ---------------- Kernel C: one fused CRF iteration, 32x16 tile, 512 threads ----------------
template <bool FINAL>
__global__ __launch_bounds__(NTHR, 8) void crf_iter_kernel(const f16* __restrict__ qin,
                                                           const f16* __restrict__ u16,
                                                           const half2v* __restrict__ wc2,
                                                           void* __restrict__ qout) {
    __shared__ __align__(16) f16 tileH[HPX2][CPAD];   // 34560 B

    const int tid = threadIdx.x;          // 0..511
    const int tx = tid & (TW - 1);        // 0..31
    const int ty = tid >> 5;              // 0..15

    // XCD band swizzle: 1024 blocks; XCD (flat%8) owns a 64-px horizontal band per batch
    const int flat = blockIdx.x;
    const int band = flat & 7;
    const int within = flat >> 3;         // 0..127
    const int b = within >> 6;
    const int r = within & 63;
    const int x0 = (r & 15) * TW;
    const int y0 = (band * 4 + (r >> 4)) * TH;
    const int x = x0 + tx;
    const int y = y0 + ty;
    const size_t plane = (size_t)HH * WW;

    // ---- async stage 20x36 halo (fp16, interleaved) straight into LDS ----
    const f16* qb = qin + (size_t)b * plane * CPAD;
    f16* lbase = &tileH[0][0];
    for (int idx = tid; idx < NCHUNK; idx += NTHR) {
        int px = idx / 3, h4 = idx - px * 3;
        int ly = px / HX2, lx = px - ly * HX2;
        int gy = refl(y0 + ly - RAD, HH);
        int gx = refl(x0 + lx - RAD, WW);
        const f16* g = qb + ((size_t)(gy * WW + gx)) * CPAD + h4 * 8;
        __builtin_amdgcn_global_load_lds(
            (const __attribute__((address_space(1))) void*)g,
            (__attribute__((address_space(3))) void*)(lbase + (size_t)idx * 8),
            16, 0, 0);
    }

    // ---- prefetch per-pixel weights + unary while staging is in flight ----
    float wcr[NTAPS + 1];
    {
        const half2v* wp = wc2 + (size_t)b * NPAIR * plane + (size_t)y * WW + x;
#pragma unroll
        for (int p = 0; p < NPAIR; p++) {
            half2v h = wp[p * plane];
            wcr[2 * p] = (float)h[0];
            wcr[2 * p + 1] = (float)h[1];
        }
    }
    const f16* ub = u16 + ((size_t)b * plane + (size_t)y * WW + x) * CPAD;
    half8 u0 = *(const half8*)(ub);
    half8 u1 = *(const half8*)(ub + 8);
    half8 u2 = *(const half8*)(ub + 16);

    __syncthreads();   // drains LDS-DMA + joins block

    // ---- 25-tap weighted gather over 21 channels, fp16 LDS, fp32 accumulate ----
    float acc[NCH];
#pragma unroll
    for (int c = 0; c < NCH; c++) acc[c] = 0.f;

    const int base = ty * HX2 + tx;
#pragma unroll
    for (int dy = 0; dy < KS; dy++) {
#pragma unroll
        for (int dx = 0; dx < KS; dx++) {
            const float w = wcr[dy * KS + dx];
            const f16* tp = &tileH[base + dy * HX2 + dx][0];
            half8 v0 = *(const half8*)(tp);
            half8 v1 = *(const half8*)(tp + 8);
            half8 v2 = *(const half8*)(tp + 16);
#pragma unroll
            for (int k = 0; k < 8; k++) acc[k]      = fmaf((float)v0[k], w, acc[k]);
#pragma unroll
            for (int k = 0; k < 8; k++) acc[8 + k]  = fmaf((float)v1[k], w, acc[8 + k]);
#pragma unroll
            for (int k = 0; k < 5; k++) acc[16 + k] = fmaf((float)v2[k], w, acc[16 + k]);
        }
    }

    // ---- logits + softmax (registers) ----
    float l[NCH];
#pragma unroll
    for (int k = 0; k < 8; k++) l[k] = (float)u0[k] - acc[k];
#pragma unroll
    for (int k = 0; k < 8; k++) l[8 + k] = (float)u1[k] - acc[8 + k];
#pragma unroll
    for (int k = 0; k < 5; k++) l[16 + k] = (float)u2[k] - acc[16 + k];

    float m = l[0];
#pragma unroll
    for (int c = 1; c < NCH; c++) m = fmaxf(m, l[c]);
    float s = 0.f;
#pragma unroll
    for (int c = 0; c < NCH; c++) { l[c] = __expf(l[c] - m); s += l[c]; }
    float is = 1.0f / s;
#pragma unroll
    for (int c = 0; c < NCH; c++) l[c] *= is;

    if (FINAL) {
        float* qo = (float*)qout + (size_t)b * NCH * plane + (size_t)y * WW + x;
#pragma unroll
        for (int c = 0; c < NCH; c++) qo[c * plane] = l[c];
    } else {
        half8* qo = (half8*)((f16*)qout + ((size_t)b * plane + (size_t)y * WW + x) * CPAD);
        float lp[CPAD];
#pragma unroll
        for (int c = 0; c < NCH; c++) lp[c] = l[c];
        lp[21] = 0.f; lp[22] = 0.f; lp[23] = 0.f;
#pragma unroll
        for (int g = 0; g < 3; g++) {
            half8 v;
#pragma unroll
            for (int k = 0; k < 8; k++) v[k] = (f16)lp[g * 8 + k];
            qo[g] = v;
        }
    }
}

extern "C" void kernel_launch(void* const* d_in, const int* in_sizes, int n_in,
                              void* d_out, int out_size, void* d_ws, size_t ws_size,
                              hipStream_t stream) {
    const float* unary = (const float*)d_in[0];   // B,21,512,512
    const float* image = (const float*)d_in[1];   // B,3,512,512
    const float* edges = (const float*)d_in[2];   // B,512,512
    float* out = (float*)d_out;                   // B,21,512,512 fp32

    const size_t plane = (size_t)HH * WW;
    char* ws = (char*)d_ws;
    half2v* wc2 = (half2v*)ws;                                   // B*13*plane half2  = 27.3 MB
    char* p1 = ws + sizeof(half2v) * BATCH * NPAIR * plane;
    f16* u16 = (f16*)p1;                                         // 25.2 MB
    char* p2 = p1 + sizeof(f16) * BATCH * plane * CPAD;
    f16* qA = (f16*)p2;                                          // 25.2 MB
    f16* qB = qA + (size_t)BATCH * plane * CPAD;                 // 25.2 MB (total ~103 MB)

    const int npix = BATCH * HH * WW;
    dim3 gridW(WW / TXW, HH / TYW, BATCH);
    dim3 blockW(TXW, TYW, 1);
    weights_kernel<<<gridW, blockW, 0, stream>>>(image, edges, wc2);
    init_kernel<<<(npix + 255) / 256, 256, 0, stream>>>(unary, qA, u16);

    const int nblk = (WW / TW) * (HH / TH) * BATCH;   // 1024
    f16* qa = qA;
    f16* qb = qB;
    for (int it = 0; it < NUM_ITERS - 1; it++) {
        crf_iter_kernel<false><<<nblk, NTHR, 0, stream>>>(qa, u16, wc2, (void*)qb);
        f16* t = qa; qa = qb; qb = t;
    }
    crf_iter_kernel<true><<<nblk, NTHR, 0, stream>>>(qa, u16, wc2, (void*)out);
}

// Round 8
// 308.728 us; speedup vs baseline: 1.9675x; 1.0789x over previous
//
#include <hip/hip_runtime.h>
#include <math.h>

#define BATCH 2
#define NCH 21
#define CPAD 24            // channels padded to 24 (48 B fp16 per pixel)
#define HH 512
#define WW 512
#define KS 5
#define RAD 2
#define NTAPS 25
#define NUM_ITERS 10

// weights-kernel tile geometry
#define TXW 32
#define TYW 8
#define HXW (TXW + 2*RAD)   // 36
#define HYW (TYW + 2*RAD)   // 12
#define HPXW (HXW * HYW)    // 432

// fused-pair kernel geometry: 32x16 inner tile, 512 threads
#define TW 32
#define TH 16
#define NTHR 512
#define SX 40               // staged tile (4-px halo for 2 iters)
#define SY 24
#define SPX (SX * SY)       // 960
#define SCHUNK (SPX * 3)    // 2880 16-byte DMA chunks
#define EX 36               // extended (iter-1 output) region
#define EY 20
#define EPX (EX * EY)       // 720
#define RING (EPX - TW*TH)  // 208 ring pixels

typedef _Float16 f16;
typedef _Float16 half8 __attribute__((ext_vector_type(8)));

__device__ __forceinline__ int refl(int i, int n) {
    if (i < 0) i = -i;
    if (i >= n) i = 2*n - 2 - i;
    return i;
}

// weight-element selector (t is a compile-time constant after unrolling)
#define WSEL(h0, h1, h2, hl, t) \
    ((t) < 8 ? (h0)[(t)] : (t) < 16 ? (h1)[(t) - 8] : (t) < 24 ? (h2)[(t) - 16] : (hl))

// ---------------- Kernel A: combined normalized weights ----------------
// layout: wcA[px][24 halfs] (taps 0..23 interleaved) + wcB16[px] (tap 24)
__global__ __launch_bounds__(256) void weights_kernel(const float* __restrict__ image,
                                                      const float* __restrict__ edges,
                                                      f16* __restrict__ wcA,
                                                      f16* __restrict__ wcB16) {
    __shared__ float sr_[HYW][HXW];
    __shared__ float sg_[HYW][HXW];
    __shared__ float sb_[HYW][HXW];
    __shared__ float se_[HYW][HXW];

    const int tx = threadIdx.x;
    const int ty = threadIdx.y;
    const int tid = ty * TXW + tx;
    const int x0 = blockIdx.x * TXW;
    const int y0 = blockIdx.y * TYW;
    const int b = blockIdx.z;
    const int x = x0 + tx;
    const int y = y0 + ty;
    const size_t plane = (size_t)HH * WW;
    const float* img = image + (size_t)b * 3 * plane;
    const float* edg = edges + (size_t)b * plane;

    for (int i = tid; i < HPXW; i += TXW * TYW) {
        int ly = i / HXW, lx = i - ly * HXW;
        int gy = refl(y0 + ly - RAD, HH);
        int gx = refl(x0 + lx - RAD, WW);
        int g = gy * WW + gx;
        sr_[ly][lx] = img[g];
        sg_[ly][lx] = img[plane + g];
        sb_[ly][lx] = img[2 * plane + g];
        se_[ly][lx] = edg[g];
    }
    __syncthreads();

    float gs[3];
    gs[0] = 1.0f; gs[1] = __expf(-1.0f / 50.0f); gs[2] = __expf(-4.0f / 50.0f);
    float gb[3];
    gb[0] = 1.0f; gb[1] = __expf(-2.0f); gb[2] = __expf(-8.0f);
    float gbs = gb[0] + 2.0f * (gb[1] + gb[2]);
    gb[0] /= gbs; gb[1] /= gbs; gb[2] /= gbs;

    const float r0 = sr_[ty + RAD][tx + RAD];
    const float g0 = sg_[ty + RAD][tx + RAD];
    const float b0 = sb_[ty + RAD][tx + RAD];
    const float e0 = se_[ty + RAD][tx + RAD];

    float wr[NTAPS], we[NTAPS];
    float sr = 0.f, se = 0.f;
#pragma unroll
    for (int dy = 0; dy < KS; dy++) {
#pragma unroll
        for (int dx = 0; dx < KS; dx++) {
            float sp = gs[abs(dy - RAD)] * gs[abs(dx - RAD)];
            float d = fabsf(sr_[ty + dy][tx + dx] - r0)
                    + fabsf(sg_[ty + dy][tx + dx] - g0)
                    + fabsf(sb_[ty + dy][tx + dx] - b0);
            float w1 = sp * __expf(-2.0f * d * d);
            float de = fabsf(se_[ty + dy][tx + dx] - e0);
            float w2 = sp * __expf(-2.0f * de * de);
            wr[dy * KS + dx] = w1;
            we[dy * KS + dx] = w2;
            sr += w1;
            se += w2;
        }
    }
    float isr = 1.0f / sr, ise = 1.0f / se;
    float wt[NTAPS];
#pragma unroll
    for (int t = 0; t < NTAPS; t++) {
        int dy = t / KS, dx = t % KS;
        float g2 = gb[abs(dy - RAD)] * gb[abs(dx - RAD)];
        wt[t] = g2 + wr[t] * isr + we[t] * ise;
    }
    const size_t pixoff = (size_t)b * plane + (size_t)y * WW + x;
    half8* wo = (half8*)(wcA + pixoff * 24);
#pragma unroll
    for (int g = 0; g < 3; g++) {
        half8 v;
#pragma unroll
        for (int k = 0; k < 8; k++) v[k] = (f16)wt[g * 8 + k];
        wo[g] = v;
    }
    wcB16[pixoff] = (f16)wt[24];
}

// ---------------- Kernel B: initial softmax -> interleaved fp16 q + fp16 unary ----------------
__global__ void init_kernel(const float* __restrict__ unary,
                            f16* __restrict__ q,
                            f16* __restrict__ u16) {
    int idx = blockIdx.x * blockDim.x + threadIdx.x;
    if (idx >= BATCH * HH * WW) return;
    int p = idx % (HH * WW);
    int b = idx / (HH * WW);
    const size_t plane = (size_t)HH * WW;
    const float* u = unary + (size_t)b * NCH * plane + p;
    float l[CPAD];
    float m = -1e30f;
#pragma unroll
    for (int c = 0; c < NCH; c++) { l[c] = u[c * plane]; m = fmaxf(m, l[c]); }
    l[21] = 0.f; l[22] = 0.f; l[23] = 0.f;

    half8* uo = (half8*)(u16 + ((size_t)b * plane + p) * CPAD);
#pragma unroll
    for (int g = 0; g < 3; g++) {
        half8 v;
#pragma unroll
        for (int k = 0; k < 8; k++) v[k] = (f16)l[g * 8 + k];
        uo[g] = v;
    }

    float s = 0.f;
    float e[CPAD];
#pragma unroll
    for (int c = 0; c < NCH; c++) { e[c] = __expf(l[c] - m); s += e[c]; }
    float is = 1.0f / s;
    e[21] = 0.f; e[22] = 0.f; e[23] = 0.f;
    half8* qo = (half8*)(q + ((size_t)b * plane + p) * CPAD);
#pragma unroll
    for (int g = 0; g < 3; g++) {
        half8 v;
#pragma unroll
        for (int k = 0; k < 8; k++) v[k] = (f16)(e[g * 8 + k] * is);
        qo[g] = v;
    }
}

// conv helper: 25-tap weighted gather from an interleaved f16 LDS tile
#define CONV_ACC(acc, lds, row0, col0, stride, W0, W1, W2, WL)                         \
    {                                                                                  \
        _Pragma("unroll")                                                              \
        for (int dy = 0; dy < KS; dy++) {                                              \
            _Pragma("unroll")                                                          \
            for (int dx = 0; dx < KS; dx++) {                                          \
                const float w = (float)WSEL(W0, W1, W2, WL, dy * KS + dx);             \
                const f16* tp = (lds) + ((size_t)((row0) + dy) * (stride) + (col0) + dx) * CPAD; \
                half8 v0 = *(const half8*)(tp);                                        \
                half8 v1 = *(const half8*)(tp + 8);                                    \
                half8 v2 = *(const half8*)(tp + 16);                                   \
                _Pragma("unroll")                                                      \
                for (int k = 0; k < 8; k++) acc[k]      = fmaf((float)v0[k], w, acc[k]);      \
                _Pragma("unroll")                                                      \
                for (int k = 0; k < 8; k++) acc[8 + k]  = fmaf((float)v1[k], w, acc[8 + k]);  \
                _Pragma("unroll")                                                      \
                for (int k = 0; k < 5; k++) acc[16 + k] = fmaf((float)v2[k], w, acc[16 + k]); \
            }                                                                          \
        }                                                                              \
    }

// ---------------- Kernel C: TWO fused CRF iterations per launch ----------------
template <bool FINAL>
__global__ __launch_bounds__(NTHR, 4) void crf_pair_kernel(const f16* __restrict__ qin,
                                                           const f16* __restrict__ u16,
                                                           const f16* __restrict__ wcA,
                                                           const f16* __restrict__ wcB16,
                                                           void* __restrict__ qout) {
    __shared__ __align__(16) f16 buf[SPX][CPAD];   // 46080 B; staged q, then reused for q'

    const int tid = threadIdx.x;          // 0..511
    const int ix = tid & (TW - 1);        // 0..31
    const int iy = tid >> 5;              // 0..15

    // XCD band swizzle: 1024 blocks; XCD (flat%8) owns 4 tile-rows per batch
    const int flat = blockIdx.x;
    const int band = flat & 7;
    const int within = flat >> 3;         // 0..127
    const int b = within >> 6;
    const int r = within & 63;
    const int x0 = (r & 15) * TW;
    const int y0 = (band * 4 + (r >> 4)) * TH;
    const int gx = x0 + ix;
    const int gy = y0 + iy;
    const size_t plane = (size_t)HH * WW;

    // ---- phase 1: async stage 24x40 q halo (4-px, for 2 iterations) ----
    const f16* qbase = qin + (size_t)b * plane * CPAD;
    f16* lbase = &buf[0][0];
    for (int idx = tid; idx < SCHUNK; idx += NTHR) {
        int px = idx / 3, h4 = idx - px * 3;
        int sly = px / SX, slx = px - sly * SX;
        int qy = refl(y0 - 4 + sly, HH);
        int qx = refl(x0 - 4 + slx, WW);
        const f16* g = qbase + ((size_t)(qy * WW + qx)) * CPAD + h4 * 8;
        __builtin_amdgcn_global_load_lds(
            (const __attribute__((address_space(1))) void*)g,
            (__attribute__((address_space(3))) void*)(lbase + (size_t)idx * 8),
            16, 0, 0);
    }

    // ---- fetch inner-pixel weights + unary (kept in registers for BOTH iterations) ----
    const size_t pixoff = (size_t)b * plane + (size_t)gy * WW + gx;
    const half8* wp = (const half8*)(wcA + pixoff * 24);
    half8 wa0 = wp[0], wa1 = wp[1], wa2 = wp[2];
    f16 wl = wcB16[pixoff];
    const half8* up = (const half8*)(u16 + pixoff * CPAD);
    half8 ui0 = up[0], ui1 = up[1], ui2 = up[2];

    // ---- ring pixel (threads 0..207): coords + weights + unary ----
    const bool has_ring = tid < RING;
    int rly = 0, rlx = 0;
    half8 wr0 = {}, wr1 = {}, wr2 = {}, ur0 = {}, ur1 = {}, ur2 = {};
    f16 wrl = (f16)0.f;
    if (has_ring) {
        int t = tid;
        if (t < 72)       { rly = t / 36;       rlx = t % 36; }
        else if (t < 144) { t -= 72;  rly = 18 + t / 36; rlx = t % 36; }
        else              { t -= 144; rly = 2 + (t >> 2); int c = t & 3; rlx = (c < 2) ? c : (c + 32); }
        int rgy = y0 + rly - 2, rgx = x0 + rlx - 2;
        int cy = min(max(rgy, 0), HH - 1);
        int cx = min(max(rgx, 0), WW - 1);
        size_t rpo = (size_t)b * plane + (size_t)cy * WW + cx;
        const half8* wpr = (const half8*)(wcA + rpo * 24);
        wr0 = wpr[0]; wr1 = wpr[1]; wr2 = wpr[2];
        wrl = wcB16[rpo];
        const half8* upr = (const half8*)(u16 + rpo * CPAD);
        ur0 = upr[0]; ur1 = upr[1]; ur2 = upr[2];
    }

    __syncthreads();   // staged q + all register loads resident

    // ---- phase 2: iteration k over the extended 36x20 region ----
    half8 qr0, qr1, qr2;   // ring q' (packed f16)
    if (has_ring) {
        float acc[NCH];
#pragma unroll
        for (int c = 0; c < NCH; c++) acc[c] = 0.f;
        CONV_ACC(acc, lbase, rly, rlx, SX, wr0, wr1, wr2, wrl);
        float l[NCH];
#pragma unroll
        for (int k = 0; k < 8; k++) l[k] = (float)ur0[k] - acc[k];
#pragma unroll
        for (int k = 0; k < 8; k++) l[8 + k] = (float)ur1[k] - acc[8 + k];
#pragma unroll
        for (int k = 0; k < 5; k++) l[16 + k] = (float)ur2[k] - acc[16 + k];
        float m = l[0];
#pragma unroll
        for (int c = 1; c < NCH; c++) m = fmaxf(m, l[c]);
        float s = 0.f;
#pragma unroll
        for (int c = 0; c < NCH; c++) { l[c] = __expf(l[c] - m); s += l[c]; }
        float is = 1.0f / s;
#pragma unroll
        for (int k = 0; k < 8; k++) qr0[k] = (f16)(l[k] * is);
#pragma unroll
        for (int k = 0; k < 8; k++) qr1[k] = (f16)(l[8 + k] * is);
#pragma unroll
        for (int k = 0; k < 5; k++) qr2[k] = (f16)(l[16 + k] * is);
        qr2[5] = (f16)0.f; qr2[6] = (f16)0.f; qr2[7] = (f16)0.f;
    }

    half8 qi0, qi1, qi2;   // inner q' (packed f16)
    {
        float acc[NCH];
#pragma unroll
        for (int c = 0; c < NCH; c++) acc[c] = 0.f;
        CONV_ACC(acc, lbase, iy + 2, ix + 2, SX, wa0, wa1, wa2, wl);
        float l[NCH];
#pragma unroll
        for (int k = 0; k < 8; k++) l[k] = (float)ui0[k] - acc[k];
#pragma unroll
        for (int k = 0; k < 8; k++) l[8 + k] = (float)ui1[k] - acc[8 + k];
#pragma unroll
        for (int k = 0; k < 5; k++) l[16 + k] = (float)ui2[k] - acc[16 + k];
        float m = l[0];
#pragma unroll
        for (int c = 1; c < NCH; c++) m = fmaxf(m, l[c]);
        float s = 0.f;
#pragma unroll
        for (int c = 0; c < NCH; c++) { l[c] = __expf(l[c] - m); s += l[c]; }
        float is = 1.0f / s;
#pragma unroll
        for (int k = 0; k < 8; k++) qi0[k] = (f16)(l[k] * is);
#pragma unroll
        for (int k = 0; k < 8; k++) qi1[k] = (f16)(l[8 + k] * is);
#pragma unroll
        for (int k = 0; k < 5; k++) qi2[k] = (f16)(l[16 + k] * is);
        qi2[5] = (f16)0.f; qi2[6] = (f16)0.f; qi2[7] = (f16)0.f;
    }

    __syncthreads();   // all reads of staged q complete

    // ---- phase 3: park q' in LDS (reuse buf; layout [EPX][24], stride EX) ----
    {
        half8* d = (half8*)(lbase + ((size_t)(iy + 2) * EX + (ix + 2)) * CPAD);
        d[0] = qi0; d[1] = qi1; d[2] = qi2;
        if (has_ring) {
            half8* dr = (half8*)(lbase + ((size_t)rly * EX + rlx) * CPAD);
            dr[0] = qr0; dr[1] = qr1; dr[2] = qr2;
        }
    }

    __syncthreads();

    // ---- phase 4: iteration k+1 at inner pixels (w,u from registers) ----
    {
        int ry[KS], rx[KS];
#pragma unroll
        for (int d = 0; d < KS; d++) {
            ry[d] = refl(gy + d - 2, HH) - (y0 - 2);
            rx[d] = refl(gx + d - 2, WW) - (x0 - 2);
        }
        float acc[NCH];
#pragma unroll
        for (int c = 0; c < NCH; c++) acc[c] = 0.f;
#pragma unroll
        for (int dy = 0; dy < KS; dy++) {
#pragma unroll
            for (int dx = 0; dx < KS; dx++) {
                const float w = (float)WSEL(wa0, wa1, wa2, wl, dy * KS + dx);
                const f16* tp = lbase + ((size_t)ry[dy] * EX + rx[dx]) * CPAD;
                half8 v0 = *(const half8*)(tp);
                half8 v1 = *(const half8*)(tp + 8);
                half8 v2 = *(const half8*)(tp + 16);
#pragma unroll
                for (int k = 0; k < 8; k++) acc[k]      = fmaf((float)v0[k], w, acc[k]);
#pragma unroll
                for (int k = 0; k < 8; k++) acc[8 + k]  = fmaf((float)v1[k], w, acc[8 + k]);
#pragma unroll
                for (int k = 0; k < 5; k++) acc[16 + k] = fmaf((float)v2[k], w, acc[16 + k]);
            }
        }
        float l[NCH];
#pragma unroll
        for (int k = 0; k < 8; k++) l[k] = (float)ui0[k] - acc[k];
#pragma unroll
        for (int k = 0; k < 8; k++) l[8 + k] = (float)ui1[k] - acc[8 + k];
#pragma unroll
        for (int k = 0; k < 5; k++) l[16 + k] = (float)ui2[k] - acc[16 + k];
        float m = l[0];
#pragma unroll
        for (int c = 1; c < NCH; c++) m = fmaxf(m, l[c]);
        float s = 0.f;
#pragma unroll
        for (int c = 0; c < NCH; c++) { l[c] = __expf(l[c] - m); s += l[c]; }
        float is = 1.0f / s;

        if (FINAL) {
            float* qo = (float*)qout + (size_t)b * NCH * plane + (size_t)gy * WW + gx;
#pragma unroll
            for (int c = 0; c < NCH; c++) qo[c * plane] = l[c] * is;
        } else {
            half8* qo = (half8*)((f16*)qout + pixoff * CPAD);
            half8 o0, o1, o2;
#pragma unroll
            for (int k = 0; k < 8; k++) o0[k] = (f16)(l[k] * is);
#pragma unroll
            for (int k = 0; k < 8; k++) o1[k] = (f16)(l[8 + k] * is);
#pragma unroll
            for (int k = 0; k < 5; k++) o2[k] = (f16)(l[16 + k] * is);
            o2[5] = (f16)0.f; o2[6] = (f16)0.f; o2[7] = (f16)0.f;
            qo[0] = o0; qo[1] = o1; qo[2] = o2;
        }
    }
}

extern "C" void kernel_launch(void* const* d_in, const int* in_sizes, int n_in,
                              void* d_out, int out_size, void* d_ws, size_t ws_size,
                              hipStream_t stream) {
    const float* unary = (const float*)d_in[0];   // B,21,512,512
    const float* image = (const float*)d_in[1];   // B,3,512,512
    const float* edges = (const float*)d_in[2];   // B,512,512
    float* out = (float*)d_out;                   // B,21,512,512 fp32

    const size_t plane = (size_t)HH * WW;
    char* ws = (char*)d_ws;
    f16* wcA = (f16*)ws;                                         // B*plane*24 f16 = 25.2 MB
    char* p1 = ws + sizeof(f16) * BATCH * plane * 24;
    f16* wcB16 = (f16*)p1;                                       // B*plane f16    =  1.0 MB
    char* p2 = p1 + sizeof(f16) * BATCH * plane;
    f16* u16 = (f16*)p2;                                         // 25.2 MB
    char* p3 = p2 + sizeof(f16) * BATCH * plane * CPAD;
    f16* qA = (f16*)p3;                                          // 25.2 MB
    f16* qB = qA + (size_t)BATCH * plane * CPAD;                 // 25.2 MB (total ~102 MB)

    const int npix = BATCH * HH * WW;
    dim3 gridW(WW / TXW, HH / TYW, BATCH);
    dim3 blockW(TXW, TYW, 1);
    weights_kernel<<<gridW, blockW, 0, stream>>>(image, edges, wcA, wcB16);
    init_kernel<<<(npix + 255) / 256, 256, 0, stream>>>(unary, qA, u16);

    const int nblk = (WW / TW) * (HH / TH) * BATCH;   // 1024
    f16* qa = qA;
    f16* qb = qB;
    const int npairs = NUM_ITERS / 2;                 // 5
    for (int it = 0; it < npairs - 1; it++) {
        crf_pair_kernel<false><<<nblk, NTHR, 0, stream>>>(qa, u16, wcA, wcB16, (void*)qb);
        f16* t = qa; qa = qb; qb = t;
    }
    crf_pair_kernel<true><<<nblk, NTHR, 0, stream>>>(qa, u16, wcA, wcB16, (void*)out);
}

// Round 9
// 287.520 us; speedup vs baseline: 2.1126x; 1.0738x over previous
//
#include <hip/hip_runtime.h>
#include <math.h>

#define BATCH 2
#define NCH 21
#define CPAD 24            // channels padded to 24 (48 B fp16 per pixel)
#define HH 512
#define WW 512
#define KS 5
#define RAD 2
#define NTAPS 25
#define NUM_ITERS 10

// weights-kernel tile geometry
#define TXW 32
#define TYW 8
#define HXW (TXW + 2*RAD)   // 36
#define HYW (TYW + 2*RAD)   // 12
#define HPXW (HXW * HYW)    // 432

// fused-pair kernel geometry: 32x16 inner tile, 512 threads
#define TW 32
#define TH 16
#define NTHR 512
#define SX 40               // staged tile (4-px halo for 2 iters)
#define SY 24
#define SPX (SX * SY)       // 960
#define SCHUNK (SPX * 3)    // 2880 16-byte DMA chunks
#define EX 36               // extended (iter-1 output) region
#define EY 20
#define EPX (EX * EY)       // 720
#define RING (EPX - TW*TH)  // 208 ring pixels

typedef _Float16 f16;
typedef _Float16 half8 __attribute__((ext_vector_type(8)));
typedef _Float16 half2v __attribute__((ext_vector_type(2)));

__device__ __forceinline__ int refl(int i, int n) {
    if (i < 0) i = -i;
    if (i >= n) i = 2*n - 2 - i;
    return i;
}

// weight-element selector (t is a compile-time constant after unrolling)
#define WSEL(h0, h1, h2, hl, t) \
    ((t) < 8 ? (h0)[(t)] : (t) < 16 ? (h1)[(t) - 8] : (t) < 24 ? (h2)[(t) - 16] : (hl))

// ---------------- Kernel A: combined normalized weights ----------------
// layout: wcA[px][24 halfs] (taps 0..23 interleaved) + wcB16[px] (tap 24)
__global__ __launch_bounds__(256) void weights_kernel(const float* __restrict__ image,
                                                      const float* __restrict__ edges,
                                                      f16* __restrict__ wcA,
                                                      f16* __restrict__ wcB16) {
    __shared__ float sr_[HYW][HXW];
    __shared__ float sg_[HYW][HXW];
    __shared__ float sb_[HYW][HXW];
    __shared__ float se_[HYW][HXW];

    const int tx = threadIdx.x;
    const int ty = threadIdx.y;
    const int tid = ty * TXW + tx;
    const int x0 = blockIdx.x * TXW;
    const int y0 = blockIdx.y * TYW;
    const int b = blockIdx.z;
    const int x = x0 + tx;
    const int y = y0 + ty;
    const size_t plane = (size_t)HH * WW;
    const float* img = image + (size_t)b * 3 * plane;
    const float* edg = edges + (size_t)b * plane;

    for (int i = tid; i < HPXW; i += TXW * TYW) {
        int ly = i / HXW, lx = i - ly * HXW;
        int gy = refl(y0 + ly - RAD, HH);
        int gx = refl(x0 + lx - RAD, WW);
        int g = gy * WW + gx;
        sr_[ly][lx] = img[g];
        sg_[ly][lx] = img[plane + g];
        sb_[ly][lx] = img[2 * plane + g];
        se_[ly][lx] = edg[g];
    }
    __syncthreads();

    float gs[3];
    gs[0] = 1.0f; gs[1] = __expf(-1.0f / 50.0f); gs[2] = __expf(-4.0f / 50.0f);
    float gb[3];
    gb[0] = 1.0f; gb[1] = __expf(-2.0f); gb[2] = __expf(-8.0f);
    float gbs = gb[0] + 2.0f * (gb[1] + gb[2]);
    gb[0] /= gbs; gb[1] /= gbs; gb[2] /= gbs;

    const float r0 = sr_[ty + RAD][tx + RAD];
    const float g0 = sg_[ty + RAD][tx + RAD];
    const float b0 = sb_[ty + RAD][tx + RAD];
    const float e0 = se_[ty + RAD][tx + RAD];

    float wr[NTAPS], we[NTAPS];
    float sr = 0.f, se = 0.f;
#pragma unroll
    for (int dy = 0; dy < KS; dy++) {
#pragma unroll
        for (int dx = 0; dx < KS; dx++) {
            float sp = gs[abs(dy - RAD)] * gs[abs(dx - RAD)];
            float d = fabsf(sr_[ty + dy][tx + dx] - r0)
                    + fabsf(sg_[ty + dy][tx + dx] - g0)
                    + fabsf(sb_[ty + dy][tx + dx] - b0);
            float w1 = sp * __expf(-2.0f * d * d);
            float de = fabsf(se_[ty + dy][tx + dx] - e0);
            float w2 = sp * __expf(-2.0f * de * de);
            wr[dy * KS + dx] = w1;
            we[dy * KS + dx] = w2;
            sr += w1;
            se += w2;
        }
    }
    float isr = 1.0f / sr, ise = 1.0f / se;
    float wt[NTAPS];
#pragma unroll
    for (int t = 0; t < NTAPS; t++) {
        int dy = t / KS, dx = t % KS;
        float g2 = gb[abs(dy - RAD)] * gb[abs(dx - RAD)];
        wt[t] = g2 + wr[t] * isr + we[t] * ise;
    }
    const size_t pixoff = (size_t)b * plane + (size_t)y * WW + x;
    half8* wo = (half8*)(wcA + pixoff * 24);
#pragma unroll
    for (int g = 0; g < 3; g++) {
        half8 v;
#pragma unroll
        for (int k = 0; k < 8; k++) v[k] = (f16)wt[g * 8 + k];
        wo[g] = v;
    }
    wcB16[pixoff] = (f16)wt[24];
}

// ---------------- Kernel B: initial softmax -> interleaved fp16 q + fp16 unary ----------------
__global__ void init_kernel(const float* __restrict__ unary,
                            f16* __restrict__ q,
                            f16* __restrict__ u16) {
    int idx = blockIdx.x * blockDim.x + threadIdx.x;
    if (idx >= BATCH * HH * WW) return;
    int p = idx % (HH * WW);
    int b = idx / (HH * WW);
    const size_t plane = (size_t)HH * WW;
    const float* u = unary + (size_t)b * NCH * plane + p;
    float l[CPAD];
    float m = -1e30f;
#pragma unroll
    for (int c = 0; c < NCH; c++) { l[c] = u[c * plane]; m = fmaxf(m, l[c]); }
    l[21] = 0.f; l[22] = 0.f; l[23] = 0.f;

    half8* uo = (half8*)(u16 + ((size_t)b * plane + p) * CPAD);
#pragma unroll
    for (int g = 0; g < 3; g++) {
        half8 v;
#pragma unroll
        for (int k = 0; k < 8; k++) v[k] = (f16)l[g * 8 + k];
        uo[g] = v;
    }

    float s = 0.f;
    float e[CPAD];
#pragma unroll
    for (int c = 0; c < NCH; c++) { e[c] = __expf(l[c] - m); s += e[c]; }
    float is = 1.0f / s;
    e[21] = 0.f; e[22] = 0.f; e[23] = 0.f;
    half8* qo = (half8*)(q + ((size_t)b * plane + p) * CPAD);
#pragma unroll
    for (int g = 0; g < 3; g++) {
        half8 v;
#pragma unroll
        for (int k = 0; k < 8; k++) v[k] = (f16)(e[g * 8 + k] * is);
        qo[g] = v;
    }
}

// packed-f16 conv helper: 25-tap gather, v_pk_fma_f16 (12 packed MACs per tap)
// acc2: half2v acc2[12]
#define CONV_ACC_PK(acc2, lds, row0, col0, stride, W0, W1, W2, WL)                     \
    {                                                                                  \
        _Pragma("unroll")                                                              \
        for (int dy = 0; dy < KS; dy++) {                                              \
            _Pragma("unroll")                                                          \
            for (int dx = 0; dx < KS; dx++) {                                          \
                const f16 wt_ = WSEL(W0, W1, W2, WL, dy * KS + dx);                    \
                const half2v wv_ = {wt_, wt_};                                         \
                const f16* tp = (lds) + ((size_t)((row0) + dy) * (stride) + (col0) + dx) * CPAD; \
                half8 v0 = *(const half8*)(tp);                                        \
                half8 v1 = *(const half8*)(tp + 8);                                    \
                half8 v2 = *(const half8*)(tp + 16);                                   \
                acc2[0]  = __builtin_elementwise_fma(wv_, __builtin_shufflevector(v0, v0, 0, 1), acc2[0]);  \
                acc2[1]  = __builtin_elementwise_fma(wv_, __builtin_shufflevector(v0, v0, 2, 3), acc2[1]);  \
                acc2[2]  = __builtin_elementwise_fma(wv_, __builtin_shufflevector(v0, v0, 4, 5), acc2[2]);  \
                acc2[3]  = __builtin_elementwise_fma(wv_, __builtin_shufflevector(v0, v0, 6, 7), acc2[3]);  \
                acc2[4]  = __builtin_elementwise_fma(wv_, __builtin_shufflevector(v1, v1, 0, 1), acc2[4]);  \
                acc2[5]  = __builtin_elementwise_fma(wv_, __builtin_shufflevector(v1, v1, 2, 3), acc2[5]);  \
                acc2[6]  = __builtin_elementwise_fma(wv_, __builtin_shufflevector(v1, v1, 4, 5), acc2[6]);  \
                acc2[7]  = __builtin_elementwise_fma(wv_, __builtin_shufflevector(v1, v1, 6, 7), acc2[7]);  \
                acc2[8]  = __builtin_elementwise_fma(wv_, __builtin_shufflevector(v2, v2, 0, 1), acc2[8]);  \
                acc2[9]  = __builtin_elementwise_fma(wv_, __builtin_shufflevector(v2, v2, 2, 3), acc2[9]);  \
                acc2[10] = __builtin_elementwise_fma(wv_, __builtin_shufflevector(v2, v2, 4, 5), acc2[10]); \
            }                                                                          \
        }                                                                              \
    }

// logits: l[c] = u[c] - acc2 (promote f16 acc to f32 here)
#define LOGITS_FROM_PK(l, acc2, U0, U1, U2)                                            \
    {                                                                                  \
        _Pragma("unroll")                                                              \
        for (int j = 0; j < 10; j++) {                                                 \
            l[2 * j]     = -(float)acc2[j][0];                                         \
            l[2 * j + 1] = -(float)acc2[j][1];                                         \
        }                                                                              \
        l[20] = -(float)acc2[10][0];                                                   \
        _Pragma("unroll")                                                              \
        for (int k = 0; k < 8; k++) l[k] += (float)U0[k];                              \
        _Pragma("unroll")                                                              \
        for (int k = 0; k < 8; k++) l[8 + k] += (float)U1[k];                          \
        _Pragma("unroll")                                                              \
        for (int k = 0; k < 5; k++) l[16 + k] += (float)U2[k];                         \
    }

// ---------------- Kernel C: TWO fused CRF iterations per launch ----------------
template <bool FINAL>
__global__ __launch_bounds__(NTHR, 4) void crf_pair_kernel(const f16* __restrict__ qin,
                                                           const f16* __restrict__ u16,
                                                           const f16* __restrict__ wcA,
                                                           const f16* __restrict__ wcB16,
                                                           void* __restrict__ qout) {
    __shared__ __align__(16) f16 buf[SPX][CPAD];   // 46080 B; staged q, then reused for q'

    const int tid = threadIdx.x;          // 0..511
    const int ix = tid & (TW - 1);        // 0..31
    const int iy = tid >> 5;              // 0..15

    // XCD band swizzle: 1024 blocks; XCD (flat%8) owns 4 tile-rows per batch
    const int flat = blockIdx.x;
    const int band = flat & 7;
    const int within = flat >> 3;         // 0..127
    const int b = within >> 6;
    const int r = within & 63;
    const int x0 = (r & 15) * TW;
    const int y0 = (band * 4 + (r >> 4)) * TH;
    const int gx = x0 + ix;
    const int gy = y0 + iy;
    const size_t plane = (size_t)HH * WW;

    // ---- phase 1: async stage 24x40 q halo (4-px, for 2 iterations) ----
    const f16* qbase = qin + (size_t)b * plane * CPAD;
    f16* lbase = &buf[0][0];
    for (int idx = tid; idx < SCHUNK; idx += NTHR) {
        int px = idx / 3, h4 = idx - px * 3;
        int sly = px / SX, slx = px - sly * SX;
        int qy = refl(y0 - 4 + sly, HH);
        int qx = refl(x0 - 4 + slx, WW);
        const f16* g = qbase + ((size_t)(qy * WW + qx)) * CPAD + h4 * 8;
        __builtin_amdgcn_global_load_lds(
            (const __attribute__((address_space(1))) void*)g,
            (__attribute__((address_space(3))) void*)(lbase + (size_t)idx * 8),
            16, 0, 0);
    }

    // ---- fetch inner-pixel weights + unary (registers, used by BOTH iterations) ----
    const size_t pixoff = (size_t)b * plane + (size_t)gy * WW + gx;
    const half8* wp = (const half8*)(wcA + pixoff * 24);
    half8 wa0 = wp[0], wa1 = wp[1], wa2 = wp[2];
    f16 wl = wcB16[pixoff];
    const half8* up = (const half8*)(u16 + pixoff * CPAD);
    half8 ui0 = up[0], ui1 = up[1], ui2 = up[2];

    // ---- ring pixel (threads 0..207): coords + weights + unary ----
    const bool has_ring = tid < RING;
    int rly = 0, rlx = 0;
    half8 wr0 = {}, wr1 = {}, wr2 = {}, ur0 = {}, ur1 = {}, ur2 = {};
    f16 wrl = (f16)0.f;
    if (has_ring) {
        int t = tid;
        if (t < 72)       { rly = t / 36;       rlx = t % 36; }
        else if (t < 144) { t -= 72;  rly = 18 + t / 36; rlx = t % 36; }
        else              { t -= 144; rly = 2 + (t >> 2); int c = t & 3; rlx = (c < 2) ? c : (c + 32); }
        int rgy = y0 + rly - 2, rgx = x0 + rlx - 2;
        int cy = min(max(rgy, 0), HH - 1);
        int cx = min(max(rgx, 0), WW - 1);
        size_t rpo = (size_t)b * plane + (size_t)cy * WW + cx;
        const half8* wpr = (const half8*)(wcA + rpo * 24);
        wr0 = wpr[0]; wr1 = wpr[1]; wr2 = wpr[2];
        wrl = wcB16[rpo];
        const half8* upr = (const half8*)(u16 + rpo * CPAD);
        ur0 = upr[0]; ur1 = upr[1]; ur2 = upr[2];
    }

    __syncthreads();   // staged q + register loads resident

    // ---- phase 2: iteration k over the extended 36x20 region (packed f16 MACs) ----
    half8 qr0, qr1, qr2;   // ring q' (packed f16)
    if (has_ring) {
        half2v acc2[11];
#pragma unroll
        for (int j = 0; j < 11; j++) acc2[j] = (half2v){(f16)0.f, (f16)0.f};
        CONV_ACC_PK(acc2, lbase, rly, rlx, SX, wr0, wr1, wr2, wrl);
        float l[NCH];
        LOGITS_FROM_PK(l, acc2, ur0, ur1, ur2);
        float m = l[0];
#pragma unroll
        for (int c = 1; c < NCH; c++) m = fmaxf(m, l[c]);
        float s = 0.f;
#pragma unroll
        for (int c = 0; c < NCH; c++) { l[c] = __expf(l[c] - m); s += l[c]; }
        float is = 1.0f / s;
#pragma unroll
        for (int k = 0; k < 8; k++) qr0[k] = (f16)(l[k] * is);
#pragma unroll
        for (int k = 0; k < 8; k++) qr1[k] = (f16)(l[8 + k] * is);
#pragma unroll
        for (int k = 0; k < 5; k++) qr2[k] = (f16)(l[16 + k] * is);
        qr2[5] = (f16)0.f; qr2[6] = (f16)0.f; qr2[7] = (f16)0.f;
    }

    half8 qi0, qi1, qi2;   // inner q' (packed f16)
    {
        half2v acc2[11];
#pragma unroll
        for (int j = 0; j < 11; j++) acc2[j] = (half2v){(f16)0.f, (f16)0.f};
        CONV_ACC_PK(acc2, lbase, iy + 2, ix + 2, SX, wa0, wa1, wa2, wl);
        float l[NCH];
        LOGITS_FROM_PK(l, acc2, ui0, ui1, ui2);
        float m = l[0];
#pragma unroll
        for (int c = 1; c < NCH; c++) m = fmaxf(m, l[c]);
        float s = 0.f;
#pragma unroll
        for (int c = 0; c < NCH; c++) { l[c] = __expf(l[c] - m); s += l[c]; }
        float is = 1.0f / s;
#pragma unroll
        for (int k = 0; k < 8; k++) qi0[k] = (f16)(l[k] * is);
#pragma unroll
        for (int k = 0; k < 8; k++) qi1[k] = (f16)(l[8 + k] * is);
#pragma unroll
        for (int k = 0; k < 5; k++) qi2[k] = (f16)(l[16 + k] * is);
        qi2[5] = (f16)0.f; qi2[6] = (f16)0.f; qi2[7] = (f16)0.f;
    }

    __syncthreads();   // all reads of staged q complete

    // ---- phase 3: park q' in LDS (reuse buf; layout [EPX][24], stride EX) ----
    {
        half8* d = (half8*)(lbase + ((size_t)(iy + 2) * EX + (ix + 2)) * CPAD);
        d[0] = qi0; d[1] = qi1; d[2] = qi2;
        if (has_ring) {
            half8* dr = (half8*)(lbase + ((size_t)rly * EX + rlx) * CPAD);
            dr[0] = qr0; dr[1] = qr1; dr[2] = qr2;
        }
    }

    __syncthreads();

    // ---- phase 4: iteration k+1 at inner pixels (w,u from registers) ----
    {
        int ry[KS], rx[KS];
#pragma unroll
        for (int d = 0; d < KS; d++) {
            ry[d] = refl(gy + d - 2, HH) - (y0 - 2);
            rx[d] = refl(gx + d - 2, WW) - (x0 - 2);
        }
        half2v acc2[11];
#pragma unroll
        for (int j = 0; j < 11; j++) acc2[j] = (half2v){(f16)0.f, (f16)0.f};
#pragma unroll
        for (int dy = 0; dy < KS; dy++) {
#pragma unroll
            for (int dx = 0; dx < KS; dx++) {
                const f16 wt_ = WSEL(wa0, wa1, wa2, wl, dy * KS + dx);
                const half2v wv_ = {wt_, wt_};
                const f16* tp = lbase + ((size_t)ry[dy] * EX + rx[dx]) * CPAD;
                half8 v0 = *(const half8*)(tp);
                half8 v1 = *(const half8*)(tp + 8);
                half8 v2 = *(const half8*)(tp + 16);
                acc2[0]  = __builtin_elementwise_fma(wv_, __builtin_shufflevector(v0, v0, 0, 1), acc2[0]);
                acc2[1]  = __builtin_elementwise_fma(wv_, __builtin_shufflevector(v0, v0, 2, 3), acc2[1]);
                acc2[2]  = __builtin_elementwise_fma(wv_, __builtin_shufflevector(v0, v0, 4, 5), acc2[2]);
                acc2[3]  = __builtin_elementwise_fma(wv_, __builtin_shufflevector(v0, v0, 6, 7), acc2[3]);
                acc2[4]  = __builtin_elementwise_fma(wv_, __builtin_shufflevector(v1, v1, 0, 1), acc2[4]);
                acc2[5]  = __builtin_elementwise_fma(wv_, __builtin_shufflevector(v1, v1, 2, 3), acc2[5]);
                acc2[6]  = __builtin_elementwise_fma(wv_, __builtin_shufflevector(v1, v1, 4, 5), acc2[6]);
                acc2[7]  = __builtin_elementwise_fma(wv_, __builtin_shufflevector(v1, v1, 6, 7), acc2[7]);
                acc2[8]  = __builtin_elementwise_fma(wv_, __builtin_shufflevector(v2, v2, 0, 1), acc2[8]);
                acc2[9]  = __builtin_elementwise_fma(wv_, __builtin_shufflevector(v2, v2, 2, 3), acc2[9]);
                acc2[10] = __builtin_elementwise_fma(wv_, __builtin_shufflevector(v2, v2, 4, 5), acc2[10]);
            }
        }
        float l[NCH];
        LOGITS_FROM_PK(l, acc2, ui0, ui1, ui2);
        float m = l[0];
#pragma unroll
        for (int c = 1; c < NCH; c++) m = fmaxf(m, l[c]);
        float s = 0.f;
#pragma unroll
        for (int c = 0; c < NCH; c++) { l[c] = __expf(l[c] - m); s += l[c]; }
        float is = 1.0f / s;

        if (FINAL) {
            float* qo = (float*)qout + (size_t)b * NCH * plane + (size_t)gy * WW + gx;
#pragma unroll
            for (int c = 0; c < NCH; c++) qo[c * plane] = l[c] * is;
        } else {
            half8* qo = (half8*)((f16*)qout + pixoff * CPAD);
            half8 o0, o1, o2;
#pragma unroll
            for (int k = 0; k < 8; k++) o0[k] = (f16)(l[k] * is);
#pragma unroll
            for (int k = 0; k < 8; k++) o1[k] = (f16)(l[8 + k] * is);
#pragma unroll
            for (int k = 0; k < 5; k++) o2[k] = (f16)(l[16 + k] * is);
            o2[5] = (f16)0.f; o2[6] = (f16)0.f; o2[7] = (f16)0.f;
            qo[0] = o0; qo[1] = o1; qo[2] = o2;
        }
    }
}

extern "C" void kernel_launch(void* const* d_in, const int* in_sizes, int n_in,
                              void* d_out, int out_size, void* d_ws, size_t ws_size,
                              hipStream_t stream) {
    const float* unary = (const float*)d_in[0];   // B,21,512,512
    const float* image = (const float*)d_in[1];   // B,3,512,512
    const float* edges = (const float*)d_in[2];   // B,512,512
    float* out = (float*)d_out;                   // B,21,512,512 fp32

    const size_t plane = (size_t)HH * WW;
    char* ws = (char*)d_ws;
    f16* wcA = (f16*)ws;                                         // B*plane*24 f16 = 25.2 MB
    char* p1 = ws + sizeof(f16) * BATCH * plane * 24;
    f16* wcB16 = (f16*)p1;                                       // B*plane f16    =  1.0 MB
    char* p2 = p1 + sizeof(f16) * BATCH * plane;
    f16* u16 = (f16*)p2;                                         // 25.2 MB
    char* p3 = p2 + sizeof(f16) * BATCH * plane * CPAD;
    f16* qA = (f16*)p3;                                          // 25.2 MB
    f16* qB = qA + (size_t)BATCH * plane * CPAD;                 // 25.2 MB (total ~102 MB)

    const int npix = BATCH * HH * WW;
    dim3 gridW(WW / TXW, HH / TYW, BATCH);
    dim3 blockW(TXW, TYW, 1);
    weights_kernel<<<gridW, blockW, 0, stream>>>(image, edges, wcA, wcB16);
    init_kernel<<<(npix + 255) / 256, 256, 0, stream>>>(unary, qA, u16);

    const int nblk = (WW / TW) * (HH / TH) * BATCH;   // 1024
    f16* qa = qA;
    f16* qb = qB;
    const int npairs = NUM_ITERS / 2;                 // 5
    for (int it = 0; it < npairs - 1; it++) {
        crf_pair_kernel<false><<<nblk, NTHR, 0, stream>>>(qa, u16, wcA, wcB16, (void*)qb);
        f16* t = qa; qa = qb; qb = t;
    }
    crf_pair_kernel<true><<<nblk, NTHR, 0, stream>>>(qa, u16, wcA, wcB16, (void*)out);
}